// Round 2
// baseline (3395.586 us; speedup 1.0000x reference)
//
#include <hip/hip_runtime.h>
#include <math.h>

#define NROWS 8192
#define DIM   512
#define HID1  1024
#define HID2  512
#define NCLS  10
#define KTOP  64

// ---------------- column stats (mean/var over batch), fp64 ----------------
template <typename T>
__global__ __launch_bounds__(256) void col_stats_partial(
    const T* __restrict__ A, int F, int rowsPerBlock,
    double* __restrict__ pSum, double* __restrict__ pSqs)
{
    int c  = blockIdx.x * 256 + threadIdx.x;
    int r0 = blockIdx.y * rowsPerBlock;
    double s = 0.0, s2 = 0.0;
    for (int r = r0; r < r0 + rowsPerBlock; ++r) {
        double v = (double)A[(size_t)r * F + c];
        s  += v;
        s2 += v * v;
    }
    pSum[(size_t)blockIdx.y * F + c] = s;
    pSqs[(size_t)blockIdx.y * F + c] = s2;
}

__global__ __launch_bounds__(256) void col_stats_final(
    const double* __restrict__ pSum, const double* __restrict__ pSqs,
    const float* __restrict__ g, const float* __restrict__ b,
    double* __restrict__ scale, double* __restrict__ shift, int F, int nPart)
{
    int c = blockIdx.x * 256 + threadIdx.x;
    double s = 0.0, s2 = 0.0;
    for (int p = 0; p < nPart; ++p) {
        s  += pSum[(size_t)p * F + c];
        s2 += pSqs[(size_t)p * F + c];
    }
    double mean = s * (1.0 / NROWS);
    double var  = s2 * (1.0 / NROWS) - mean * mean;
    double sc   = (double)g[c] / sqrt(var + 1e-5);
    scale[c] = sc;
    shift[c] = (double)b[c] - mean * sc;
}

// ---------------- fused affine(A) @ W^T + bias -> tanh, fp64 ----------------
// out[m][f] = tanh( sum_k (A[m][k]*scl[k]+sft[k]) * W[f][k] + bias[f] )
template <typename T>
__global__ __launch_bounds__(256) void gemm_affine_tanh(
    const T* __restrict__ A, const double* __restrict__ scl, const double* __restrict__ sft,
    const float* __restrict__ W, const float* __restrict__ bias,
    double* __restrict__ out, int Kd, int F)
{
    __shared__ double aSh[16][68];
    __shared__ double wSh[16][68];
    const int t = threadIdx.x;
    const int fBase = blockIdx.x * 64;
    const int mBase = blockIdx.y * 64;
    const int tm = t & 15, tf = t >> 4;
    const int sm = t >> 2, sk = (t & 3) * 4;
    double acc[4][4] = {};
    for (int k0 = 0; k0 < Kd; k0 += 16) {
        double a0, a1, a2, a3;
        if constexpr (sizeof(T) == 4) {
            float4 av = *(const float4*)&A[(size_t)(mBase + sm) * Kd + k0 + sk];
            a0 = av.x; a1 = av.y; a2 = av.z; a3 = av.w;
        } else {
            const double2* ap = (const double2*)&A[(size_t)(mBase + sm) * Kd + k0 + sk];
            double2 d0 = ap[0], d1 = ap[1];
            a0 = d0.x; a1 = d0.y; a2 = d1.x; a3 = d1.y;
        }
        const double2* sp = (const double2*)&scl[k0 + sk];
        const double2* hp = (const double2*)&sft[k0 + sk];
        double2 s0 = sp[0], s1 = sp[1];
        double2 h0 = hp[0], h1 = hp[1];
        aSh[sk + 0][sm] = a0 * s0.x + h0.x;
        aSh[sk + 1][sm] = a1 * s0.y + h0.y;
        aSh[sk + 2][sm] = a2 * s1.x + h1.x;
        aSh[sk + 3][sm] = a3 * s1.y + h1.y;
        float4 wv = *(const float4*)&W[(size_t)(fBase + sm) * Kd + k0 + sk];
        wSh[sk + 0][sm] = wv.x;
        wSh[sk + 1][sm] = wv.y;
        wSh[sk + 2][sm] = wv.z;
        wSh[sk + 3][sm] = wv.w;
        __syncthreads();
        #pragma unroll
        for (int kk = 0; kk < 16; ++kk) {
            double a4[4], w4[4];
            #pragma unroll
            for (int q = 0; q < 4; ++q) { a4[q] = aSh[kk][tm * 4 + q]; w4[q] = wSh[kk][tf * 4 + q]; }
            #pragma unroll
            for (int i = 0; i < 4; ++i)
                #pragma unroll
                for (int j = 0; j < 4; ++j)
                    acc[i][j] += a4[i] * w4[j];
        }
        __syncthreads();
    }
    #pragma unroll
    for (int i = 0; i < 4; ++i) {
        int m = mBase + tm * 4 + i;
        #pragma unroll
        for (int j = 0; j < 4; ++j) {
            int f = fBase + tf * 4 + j;
            out[(size_t)m * F + f] = tanh(acc[i][j] + (double)bias[f]);
        }
    }
}

// ---------------- row squared norms of BN'd features, fp64 ----------------
__global__ __launch_bounds__(256) void row_sqnorm(
    const double* __restrict__ Y, const double* __restrict__ scl, const double* __restrict__ sft,
    double* __restrict__ sq)
{
    const int wid = threadIdx.x >> 6, lane = threadIdx.x & 63;
    const int r = blockIdx.x * 4 + wid;
    double s = 0.0;
    for (int c = lane; c < HID2; c += 64) {
        double v = Y[(size_t)r * HID2 + c] * scl[c] + sft[c];
        s += v * v;
    }
    #pragma unroll
    for (int off = 32; off > 0; off >>= 1) s += __shfl_down(s, off);
    if (lane == 0) sq[r] = s;
}

// ---------------- sim chunk: simbuf[i][j] = -d2(f_i, f_j), diag -inf ----------------
__global__ __launch_bounds__(256) void sim_gemm(
    const double* __restrict__ Y, const double* __restrict__ scl, const double* __restrict__ sft,
    const double* __restrict__ sq, double* __restrict__ simbuf, int rowBase)
{
    __shared__ double aSh[16][68];
    __shared__ double bSh[16][68];
    const int t = threadIdx.x;
    const int jBase = blockIdx.x * 64;
    const int iBase = rowBase + blockIdx.y * 64;
    const int tm = t & 15, tf = t >> 4;
    const int sm = t >> 2, sk = (t & 3) * 4;
    double acc[4][4] = {};
    for (int k0 = 0; k0 < HID2; k0 += 16) {
        const double2* sp = (const double2*)&scl[k0 + sk];
        const double2* hp = (const double2*)&sft[k0 + sk];
        double2 s0 = sp[0], s1 = sp[1];
        double2 h0 = hp[0], h1 = hp[1];
        const double2* ap = (const double2*)&Y[(size_t)(iBase + sm) * HID2 + k0 + sk];
        double2 av0 = ap[0], av1 = ap[1];
        aSh[sk + 0][sm] = av0.x * s0.x + h0.x;
        aSh[sk + 1][sm] = av0.y * s0.y + h0.y;
        aSh[sk + 2][sm] = av1.x * s1.x + h1.x;
        aSh[sk + 3][sm] = av1.y * s1.y + h1.y;
        const double2* bp = (const double2*)&Y[(size_t)(jBase + sm) * HID2 + k0 + sk];
        double2 bv0 = bp[0], bv1 = bp[1];
        bSh[sk + 0][sm] = bv0.x * s0.x + h0.x;
        bSh[sk + 1][sm] = bv0.y * s0.y + h0.y;
        bSh[sk + 2][sm] = bv1.x * s1.x + h1.x;
        bSh[sk + 3][sm] = bv1.y * s1.y + h1.y;
        __syncthreads();
        #pragma unroll
        for (int kk = 0; kk < 16; ++kk) {
            double a4[4], b4[4];
            #pragma unroll
            for (int q = 0; q < 4; ++q) { a4[q] = aSh[kk][tm * 4 + q]; b4[q] = bSh[kk][tf * 4 + q]; }
            #pragma unroll
            for (int i = 0; i < 4; ++i)
                #pragma unroll
                for (int j = 0; j < 4; ++j)
                    acc[i][j] += a4[i] * b4[j];
        }
        __syncthreads();
    }
    #pragma unroll
    for (int i = 0; i < 4; ++i) {
        int gi = iBase + tm * 4 + i;
        double sqi = sq[gi];
        #pragma unroll
        for (int j = 0; j < 4; ++j) {
            int gj = jBase + tf * 4 + j;
            double d2 = sqi + sq[gj] - 2.0 * acc[i][j];
            d2 = fmax(d2, 0.0);
            double s = (gi == gj) ? -INFINITY : -d2;   // rank by -d2 (monotone in -dist)
            simbuf[(size_t)(gi - rowBase) * NROWS + gj] = s;
        }
    }
}

// ---------------- per-row top-K -> softmax -> class scatter ----------------
__device__ __forceinline__ unsigned long long dKey(double v) {
    unsigned long long b = (unsigned long long)__double_as_longlong(v);
    return (b & 0x8000000000000000ull) ? ~b : (b | 0x8000000000000000ull);
}
__device__ __forceinline__ double keyToD(unsigned long long k) {
    unsigned long long b = (k & 0x8000000000000000ull) ? (k ^ 0x8000000000000000ull) : ~k;
    return __longlong_as_double((long long)b);
}

__global__ __launch_bounds__(256) void topk_softmax(
    const double* __restrict__ simbuf, const int* __restrict__ labels,
    float* __restrict__ out, int rowBase)
{
    __shared__ int                redI[4];
    __shared__ unsigned long long redU[4];
    __shared__ double             redF[4];
    __shared__ double             cls[NCLS];
    const int t = threadIdx.x;
    const int wid = t >> 6, lane = t & 63;
    const int row = blockIdx.x;
    const double* srow = simbuf + (size_t)row * NROWS;

    unsigned long long key[32];
    #pragma unroll
    for (int ii = 0; ii < 32; ++ii) key[ii] = dKey(srow[t + ii * 256]);

    // row max key (= min d2)
    unsigned long long kmax = 0ull;
    #pragma unroll
    for (int ii = 0; ii < 32; ++ii) kmax = max(kmax, key[ii]);
    #pragma unroll
    for (int off = 32; off > 0; off >>= 1)
        kmax = max(kmax, (unsigned long long)__shfl_down(kmax, off));
    if (lane == 0) redU[wid] = kmax;
    if (t < NCLS) cls[t] = 0.0;
    __syncthreads();
    kmax = max(max(redU[0], redU[1]), max(redU[2], redU[3]));
    double d2min = -keyToD(kmax);
    double distMin = (d2min > 1e-9) ? sqrt(d2min) : 0.0;
    __syncthreads();

    // binary search for the KTOP-th largest key value T
    unsigned long long lo = 0ull, hi = 0x8000000000000000ull;
    while (lo < hi) {
        unsigned long long mid = lo + ((hi - lo + 1ull) >> 1);
        int cnt = 0;
        #pragma unroll
        for (int ii = 0; ii < 32; ++ii) cnt += (key[ii] >= mid) ? 1 : 0;
        #pragma unroll
        for (int off = 32; off > 0; off >>= 1) cnt += __shfl_down(cnt, off);
        if (lane == 0) redI[wid] = cnt;
        __syncthreads();
        int tot = redI[0] + redI[1] + redI[2] + redI[3];
        __syncthreads();
        if (tot >= KTOP) lo = mid; else hi = mid - 1ull;
    }
    const unsigned long long T = lo;

    // softmax over kept + class accumulate (fp64)
    double S = 0.0;
    #pragma unroll
    for (int ii = 0; ii < 32; ++ii) {
        if (key[ii] >= T) {
            double d2 = -keyToD(key[ii]);
            double dist = (d2 > 1e-9) ? sqrt(d2) : 0.0;
            double w = exp(distMin - dist);
            S += w;
            atomicAdd(&cls[labels[t + ii * 256]], w);
        }
    }
    #pragma unroll
    for (int off = 32; off > 0; off >>= 1) S += __shfl_down(S, off);
    if (lane == 0) redF[wid] = S;
    __syncthreads();
    double Stot = redF[0] + redF[1] + redF[2] + redF[3];

    if (t < NCLS) {
        double p = cls[t] / Stot;
        p = fmin(fmax(p, 0.0), 1.0);
        out[(size_t)(rowBase + row) * NCLS + t] = (float)p;
    }
}

extern "C" void kernel_launch(void* const* d_in, const int* in_sizes, int n_in,
                              void* d_out, int out_size, void* d_ws, size_t ws_size,
                              hipStream_t stream)
{
    const float* x     = (const float*)d_in[0];
    // d_in[1] = x_n == x bit-exactly (self-neighbor mode) -> features computed once
    const int*   y_n   = (const int*)d_in[2];
    const float* ibn_g = (const float*)d_in[3];
    const float* ibn_b = (const float*)d_in[4];
    const float* W1    = (const float*)d_in[5];
    const float* b1    = (const float*)d_in[6];
    const float* g1    = (const float*)d_in[7];
    const float* bb1   = (const float*)d_in[8];
    const float* W2    = (const float*)d_in[9];
    const float* b2    = (const float*)d_in[10];
    const float* g2    = (const float*)d_in[11];
    const float* bb2   = (const float*)d_in[12];
    float* out = (float*)d_out;

    char* ws = (char*)d_ws;
    // region A (64 MiB): y1 during features, then reused as simbuf (1024 x 8192 f64)
    double* y1   = (double*)(ws);
    double* simb = (double*)(ws);
    double* y2   = (double*)(ws + 67108864);         // 8192*512 f64 = 32 MiB
    double* pSum = (double*)(ws + 100663296);        // 64*1024 f64 = 512 KiB
    double* pSqs = (double*)(ws + 101187584);        // 512 KiB
    double* prm  = (double*)(ws + 101711872);        // 6*1024 f64
    double* scale0 = prm;           double* shift0 = prm + 1024;
    double* scale1 = prm + 2048;    double* shift1 = prm + 3072;
    double* scale2 = prm + 4096;    double* shift2 = prm + 5120;
    double* sqv  = (double*)(ws + 101761024);        // 8192 f64

    dim3 blk(256);
    const int RPB = NROWS / 64;  // 128 rows per stats block, 64 partials

    // input BN params
    col_stats_partial<float><<<dim3(DIM / 256, 64), blk, 0, stream>>>(x, DIM, RPB, pSum, pSqs);
    col_stats_final<<<dim3(DIM / 256), blk, 0, stream>>>(pSum, pSqs, ibn_g, ibn_b, scale0, shift0, DIM, 64);
    // layer 1
    gemm_affine_tanh<float><<<dim3(HID1 / 64, NROWS / 64), blk, 0, stream>>>(x, scale0, shift0, W1, b1, y1, DIM, HID1);
    col_stats_partial<double><<<dim3(HID1 / 256, 64), blk, 0, stream>>>(y1, HID1, RPB, pSum, pSqs);
    col_stats_final<<<dim3(HID1 / 256), blk, 0, stream>>>(pSum, pSqs, g1, bb1, scale1, shift1, HID1, 64);
    // layer 2
    gemm_affine_tanh<double><<<dim3(HID2 / 64, NROWS / 64), blk, 0, stream>>>(y1, scale1, shift1, W2, b2, y2, HID1, HID2);
    col_stats_partial<double><<<dim3(HID2 / 256, 64), blk, 0, stream>>>(y2, HID2, RPB, pSum, pSqs);
    col_stats_final<<<dim3(HID2 / 256), blk, 0, stream>>>(pSum, pSqs, g2, bb2, scale2, shift2, HID2, 64);
    // feature squared norms
    row_sqnorm<<<dim3(NROWS / 4), blk, 0, stream>>>(y2, scale2, shift2, sqv);
    // chunked all-pairs sim + per-row topK/softmax (y1 region reused as simbuf)
    for (int ch = 0; ch < 8; ++ch) {
        int rowBase = ch * 1024;
        sim_gemm<<<dim3(NROWS / 64, 1024 / 64), blk, 0, stream>>>(y2, scale2, shift2, sqv, simb, rowBase);
        topk_softmax<<<dim3(1024), blk, 0, stream>>>(simb, y_n, out, rowBase);
    }
}

// Round 3
// 1439.819 us; speedup vs baseline: 2.3583x; 2.3583x over previous
//
#include <hip/hip_runtime.h>
#include <math.h>

#define NROWS 8192
#define DIM   512
#define HID1  1024
#define HID2  512
#define NCLS  10
#define KTOP  64
#define KPACK 1024      // packed row: [hi(512) | lo(512)]
#define KFULL 1536      // logical GEMM K: hi*hi + hi*lo + lo*hi
#define EPSBAND 0.02f   // d2 ambiguity half-band; approx err <= ~2e-3

typedef __attribute__((ext_vector_type(8))) short short8;
typedef __attribute__((ext_vector_type(4))) float f32x4;

__device__ __forceinline__ unsigned short f2bf(float x) {
    unsigned u = __float_as_uint(x);
    u += 0x7FFFu + ((u >> 16) & 1u);   // RN-even
    return (unsigned short)(u >> 16);
}
__device__ __forceinline__ float bf2f(unsigned short h) {
    return __uint_as_float(((unsigned)h) << 16);
}

// ---------------- column stats (mean/var over batch), fp64 ----------------
template <typename T>
__global__ __launch_bounds__(256) void col_stats_partial(
    const T* __restrict__ A, int F, int rowsPerBlock,
    double* __restrict__ pSum, double* __restrict__ pSqs)
{
    int c  = blockIdx.x * 256 + threadIdx.x;
    int r0 = blockIdx.y * rowsPerBlock;
    double s = 0.0, s2 = 0.0;
    for (int r = r0; r < r0 + rowsPerBlock; ++r) {
        double v = (double)A[(size_t)r * F + c];
        s  += v;
        s2 += v * v;
    }
    pSum[(size_t)blockIdx.y * F + c] = s;
    pSqs[(size_t)blockIdx.y * F + c] = s2;
}

__global__ __launch_bounds__(256) void col_stats_final(
    const double* __restrict__ pSum, const double* __restrict__ pSqs,
    const float* __restrict__ g, const float* __restrict__ b,
    double* __restrict__ scale, double* __restrict__ shift, int F, int nPart)
{
    int c = blockIdx.x * 256 + threadIdx.x;
    double s = 0.0, s2 = 0.0;
    for (int p = 0; p < nPart; ++p) {
        s  += pSum[(size_t)p * F + c];
        s2 += pSqs[(size_t)p * F + c];
    }
    double mean = s * (1.0 / NROWS);
    double var  = s2 * (1.0 / NROWS) - mean * mean;
    double sc   = (double)g[c] / sqrt(var + 1e-5);
    scale[c] = sc;
    shift[c] = (double)b[c] - mean * sc;
}

// ---------------- fused affine(A) @ W^T + bias -> tanh, fp64 ----------------
template <typename T>
__global__ __launch_bounds__(256) void gemm_affine_tanh(
    const T* __restrict__ A, const double* __restrict__ scl, const double* __restrict__ sft,
    const float* __restrict__ W, const float* __restrict__ bias,
    double* __restrict__ out, int Kd, int F)
{
    __shared__ double aSh[16][68];
    __shared__ double wSh[16][68];
    const int t = threadIdx.x;
    const int fBase = blockIdx.x * 64;
    const int mBase = blockIdx.y * 64;
    const int tm = t & 15, tf = t >> 4;
    const int sm = t >> 2, sk = (t & 3) * 4;
    double acc[4][4] = {};
    for (int k0 = 0; k0 < Kd; k0 += 16) {
        double a0, a1, a2, a3;
        if constexpr (sizeof(T) == 4) {
            float4 av = *(const float4*)&A[(size_t)(mBase + sm) * Kd + k0 + sk];
            a0 = av.x; a1 = av.y; a2 = av.z; a3 = av.w;
        } else {
            const double2* ap = (const double2*)&A[(size_t)(mBase + sm) * Kd + k0 + sk];
            double2 d0 = ap[0], d1 = ap[1];
            a0 = d0.x; a1 = d0.y; a2 = d1.x; a3 = d1.y;
        }
        const double2* sp = (const double2*)&scl[k0 + sk];
        const double2* hp = (const double2*)&sft[k0 + sk];
        double2 s0 = sp[0], s1 = sp[1];
        double2 h0 = hp[0], h1 = hp[1];
        aSh[sk + 0][sm] = a0 * s0.x + h0.x;
        aSh[sk + 1][sm] = a1 * s0.y + h0.y;
        aSh[sk + 2][sm] = a2 * s1.x + h1.x;
        aSh[sk + 3][sm] = a3 * s1.y + h1.y;
        float4 wv = *(const float4*)&W[(size_t)(fBase + sm) * Kd + k0 + sk];
        wSh[sk + 0][sm] = wv.x;
        wSh[sk + 1][sm] = wv.y;
        wSh[sk + 2][sm] = wv.z;
        wSh[sk + 3][sm] = wv.w;
        __syncthreads();
        #pragma unroll
        for (int kk = 0; kk < 16; ++kk) {
            double a4[4], w4[4];
            #pragma unroll
            for (int q = 0; q < 4; ++q) { a4[q] = aSh[kk][tm * 4 + q]; w4[q] = wSh[kk][tf * 4 + q]; }
            #pragma unroll
            for (int i = 0; i < 4; ++i)
                #pragma unroll
                for (int j = 0; j < 4; ++j)
                    acc[i][j] += a4[i] * w4[j];
        }
        __syncthreads();
    }
    #pragma unroll
    for (int i = 0; i < 4; ++i) {
        int m = mBase + tm * 4 + i;
        #pragma unroll
        for (int j = 0; j < 4; ++j) {
            int f = fBase + tf * 4 + j;
            out[(size_t)m * F + f] = tanh(acc[i][j] + (double)bias[f]);
        }
    }
}

// ---------------- pack: f = y2*scl+sft (fp64) -> R=[hi|lo] bf16, sqf fp32 ----------------
__global__ __launch_bounds__(256) void pack_features(
    const double* __restrict__ y2, const double* __restrict__ scl, const double* __restrict__ sft,
    unsigned short* __restrict__ R, float* __restrict__ sqf)
{
    __shared__ double red[4];
    const int r = blockIdx.x;
    const int t = threadIdx.x;
    const int wid = t >> 6, lane = t & 63;
    const int c = t * 2;
    double2 y  = *(const double2*)&y2[(size_t)r * HID2 + c];
    double2 s2 = *(const double2*)&scl[c];
    double2 h2 = *(const double2*)&sft[c];
    double f0 = y.x * s2.x + h2.x;
    double f1 = y.y * s2.y + h2.y;
    unsigned short hi0 = f2bf((float)f0);
    unsigned short hi1 = f2bf((float)f1);
    unsigned short lo0 = f2bf((float)(f0 - (double)bf2f(hi0)));
    unsigned short lo1 = f2bf((float)(f1 - (double)bf2f(hi1)));
    unsigned short* Rr = R + (size_t)r * KPACK;
    Rr[c]           = hi0; Rr[c + 1]           = hi1;
    Rr[HID2 + c]    = lo0; Rr[HID2 + c + 1]    = lo1;
    double s = f0 * f0 + f1 * f1;
    #pragma unroll
    for (int off = 32; off > 0; off >>= 1) s += __shfl_down(s, off);
    if (lane == 0) red[wid] = s;
    __syncthreads();
    if (t == 0) sqf[r] = (float)(red[0] + red[1] + red[2] + red[3]);
}

// ---------------- sim chunk via bf16 MFMA: simbuf[i][j] = -(d2 approx) ----------------
__global__ __launch_bounds__(256) void sim_mfma(
    const unsigned short* __restrict__ R, const float* __restrict__ sqf,
    float* __restrict__ simbuf, int rowBase)
{
    __shared__ unsigned short aT[128 * 64];
    __shared__ unsigned short bT[128 * 64];
    const int t = threadIdx.x;
    const int wid = t >> 6, lane = t & 63;
    const int wr = wid >> 1, wc = wid & 1;
    const int iBase = rowBase + blockIdx.y * 128;
    const int jBase = blockIdx.x * 128;
    const int srow = lane >> 3;          // 0..7
    const int skk  = (lane & 7) * 8;     // k element offset within 64

    f32x4 zero = {0.f, 0.f, 0.f, 0.f};
    f32x4 acc[4][4];
    #pragma unroll
    for (int m = 0; m < 4; ++m)
        #pragma unroll
        for (int n = 0; n < 4; ++n) acc[m][n] = zero;

    for (int k0 = 0; k0 < KFULL; k0 += 64) {
        const int aSrc = (k0 < 512)  ? k0 : (k0 - 512);   // [hi, hi, lo]
        const int bSrc = (k0 < 1024) ? k0 : (k0 - 1024);  // [hi, lo, hi]
        #pragma unroll
        for (int c = 0; c < 4; ++c) {
            int row = c * 32 + wid * 8 + srow;
            const unsigned short* gpA = R + (size_t)(iBase + row) * KPACK + aSrc + skk;
            const unsigned short* gpB = R + (size_t)(jBase + row) * KPACK + bSrc + skk;
            unsigned short* lpA = &aT[(c * 4 + wid) * 512];  // 1 KiB per wave-call, wave-uniform
            unsigned short* lpB = &bT[(c * 4 + wid) * 512];
            __builtin_amdgcn_global_load_lds((const __attribute__((address_space(1))) void*)gpA,
                (__attribute__((address_space(3))) void*)lpA, 16, 0, 0);
            __builtin_amdgcn_global_load_lds((const __attribute__((address_space(1))) void*)gpB,
                (__attribute__((address_space(3))) void*)lpB, 16, 0, 0);
        }
        __syncthreads();
        #pragma unroll
        for (int ks = 0; ks < 2; ++ks) {
            short8 aF[4], bF[4];
            #pragma unroll
            for (int m = 0; m < 4; ++m) {
                int rA = wr * 64 + m * 16 + (lane & 15);
                aF[m] = *(const short8*)&aT[rA * 64 + ks * 32 + (lane >> 4) * 8];
            }
            #pragma unroll
            for (int n = 0; n < 4; ++n) {
                int rB = wc * 64 + n * 16 + (lane & 15);
                bF[n] = *(const short8*)&bT[rB * 64 + ks * 32 + (lane >> 4) * 8];
            }
            #pragma unroll
            for (int m = 0; m < 4; ++m)
                #pragma unroll
                for (int n = 0; n < 4; ++n)
                    acc[m][n] = __builtin_amdgcn_mfma_f32_16x16x32_bf16(aF[m], bF[n], acc[m][n], 0, 0, 0);
        }
        __syncthreads();
    }

    #pragma unroll
    for (int m = 0; m < 4; ++m) {
        #pragma unroll
        for (int n = 0; n < 4; ++n) {
            int j = jBase + wc * 64 + n * 16 + (lane & 15);
            float sqj = sqf[j];
            #pragma unroll
            for (int r = 0; r < 4; ++r) {
                int i = iBase + wr * 64 + m * 16 + (lane >> 4) * 4 + r;
                float d2 = sqf[i] + sqj - 2.0f * acc[m][n][r];
                d2 = fmaxf(d2, 0.f);
                float s = (i == j) ? -INFINITY : -d2;
                simbuf[(size_t)(i - rowBase) * NROWS + j] = s;
            }
        }
    }
}

// ---------------- top-K (fp32 rank) + fp64 band refinement + softmax ----------------
__device__ __forceinline__ unsigned fKey(float v) {
    unsigned b = __float_as_uint(v);
    return (b & 0x80000000u) ? ~b : (b | 0x80000000u);
}
__device__ __forceinline__ float keyToFloat(unsigned k) {
    unsigned b = (k & 0x80000000u) ? (k ^ 0x80000000u) : ~k;
    return __uint_as_float(b);
}

__global__ __launch_bounds__(256) void topk_refine(
    const float* __restrict__ simbuf,
    const double* __restrict__ y2, const double* __restrict__ scl, const double* __restrict__ sft,
    const int* __restrict__ labels, float* __restrict__ out, int rowBase)
{
    __shared__ int      redI[4];
    __shared__ unsigned redU[4];
    __shared__ float    redF[4];
    __shared__ float    cls[NCLS];
    __shared__ int      bandJ[128];
    __shared__ double   bandD2[128];
    __shared__ unsigned char keepB[128];
    __shared__ int      bandCnt;

    const int t = threadIdx.x;
    const int wid = t >> 6, lane = t & 63;
    const int row = blockIdx.x;
    const int gi = rowBase + row;
    const float* srow = simbuf + (size_t)row * NROWS;

    unsigned key[32];
    #pragma unroll
    for (int ii = 0; ii < 32; ++ii) key[ii] = fKey(srow[t + ii * 256]);

    // global row max (nearest neighbor), fp32 approx — common softmax shift
    unsigned kmax = 0u;
    #pragma unroll
    for (int ii = 0; ii < 32; ++ii) kmax = max(kmax, key[ii]);
    #pragma unroll
    for (int off = 32; off > 0; off >>= 1) kmax = max(kmax, (unsigned)__shfl_down(kmax, off));
    if (lane == 0) redU[wid] = kmax;
    if (t == 0) bandCnt = 0;
    if (t < NCLS) cls[t] = 0.f;
    __syncthreads();
    kmax = max(max(redU[0], redU[1]), max(redU[2], redU[3]));
    float d2min = fmaxf(-keyToFloat(kmax), 0.f);
    float distMin = (d2min > 1e-9f) ? sqrtf(d2min) : 0.f;
    __syncthreads();

    // binary search: T64 = 64th largest fp32 key
    unsigned lo = 0u, hi = 0xFFFFFFFFu;
    while (lo < hi) {
        unsigned mid = (unsigned)(((unsigned long long)lo + hi + 1ull) >> 1);
        int cnt = 0;
        #pragma unroll
        for (int ii = 0; ii < 32; ++ii) cnt += (key[ii] >= mid) ? 1 : 0;
        #pragma unroll
        for (int off = 32; off > 0; off >>= 1) cnt += __shfl_down(cnt, off);
        if (lane == 0) redI[wid] = cnt;
        __syncthreads();
        int tot = redI[0] + redI[1] + redI[2] + redI[3];
        __syncthreads();
        if (tot >= KTOP) lo = mid; else hi = mid - 1u;
    }
    const float s64 = keyToFloat(lo);
    const unsigned Ku = fKey(s64 + EPSBAND);
    const unsigned Kl = fKey(s64 - EPSBAND);

    // nSafe = count(key >= Ku): definitely in true top-64 (<= 63 by construction)
    int cnt = 0;
    #pragma unroll
    for (int ii = 0; ii < 32; ++ii) cnt += (key[ii] >= Ku) ? 1 : 0;
    #pragma unroll
    for (int off = 32; off > 0; off >>= 1) cnt += __shfl_down(cnt, off);
    if (lane == 0) redI[wid] = cnt;
    __syncthreads();
    const int nSafe = redI[0] + redI[1] + redI[2] + redI[3];
    const int Rslots = KTOP - nSafe;

    // collect ambiguous band: Kl <= key < Ku
    #pragma unroll
    for (int ii = 0; ii < 32; ++ii) {
        if (key[ii] >= Kl && key[ii] < Ku) {
            int pos = atomicAdd(&bandCnt, 1);
            if (pos < 128) bandJ[pos] = t + ii * 256;
        }
    }
    __syncthreads();
    const int nb = min(bandCnt, 128);

    // exact fp64 d2 for band members (one wave per member)
    for (int c2 = wid; c2 < nb; c2 += 4) {
        int j = bandJ[c2];
        double s = 0.0;
        for (int d = lane; d < HID2; d += 64) {
            double sc = scl[d], sh = sft[d];
            double fi = y2[(size_t)gi * HID2 + d] * sc + sh;
            double fj = y2[(size_t)j  * HID2 + d] * sc + sh;
            double df = fi - fj;
            s += df * df;
        }
        #pragma unroll
        for (int off = 32; off > 0; off >>= 1) s += __shfl_down(s, off);
        if (lane == 0) bandD2[c2] = s;
    }
    __syncthreads();

    // rank band by (d2 asc, index asc); keep top Rslots
    for (int c2 = t; c2 < nb; c2 += 256) {
        double d2c = bandD2[c2];
        int jc = bandJ[c2];
        int rank = 0;
        for (int q = 0; q < nb; ++q) {
            double dq = bandD2[q];
            rank += (dq < d2c || (dq == d2c && bandJ[q] < jc)) ? 1 : 0;
        }
        keepB[c2] = (rank < Rslots) ? 1 : 0;
    }
    __syncthreads();

    // softmax accumulate: safe set (fp32 d2) + kept band (fp64 d2)
    float S = 0.f;
    #pragma unroll
    for (int ii = 0; ii < 32; ++ii) {
        if (key[ii] >= Ku) {
            float d2 = -keyToFloat(key[ii]);
            float dist = (d2 > 1e-9f) ? sqrtf(d2) : 0.f;
            float w = expf(distMin - dist);
            S += w;
            atomicAdd(&cls[labels[t + ii * 256]], w);
        }
    }
    for (int c2 = t; c2 < nb; c2 += 256) {
        if (keepB[c2]) {
            double dd = bandD2[c2];
            float dist = (dd > 1e-9) ? (float)sqrt(dd) : 0.f;
            float w = expf(distMin - dist);
            S += w;
            atomicAdd(&cls[labels[bandJ[c2]]], w);
        }
    }
    #pragma unroll
    for (int off = 32; off > 0; off >>= 1) S += __shfl_down(S, off);
    if (lane == 0) redF[wid] = S;
    __syncthreads();
    float Stot = redF[0] + redF[1] + redF[2] + redF[3];

    if (t < NCLS) {
        float p = cls[t] / Stot;
        out[(size_t)gi * NCLS + t] = fminf(fmaxf(p, 0.f), 1.f);
    }
}

extern "C" void kernel_launch(void* const* d_in, const int* in_sizes, int n_in,
                              void* d_out, int out_size, void* d_ws, size_t ws_size,
                              hipStream_t stream)
{
    const float* x     = (const float*)d_in[0];
    // d_in[1] = x_n == x bit-exactly (self-neighbor mode) -> features computed once
    const int*   y_n   = (const int*)d_in[2];
    const float* ibn_g = (const float*)d_in[3];
    const float* ibn_b = (const float*)d_in[4];
    const float* W1    = (const float*)d_in[5];
    const float* b1    = (const float*)d_in[6];
    const float* g1    = (const float*)d_in[7];
    const float* bb1   = (const float*)d_in[8];
    const float* W2    = (const float*)d_in[9];
    const float* b2    = (const float*)d_in[10];
    const float* g2    = (const float*)d_in[11];
    const float* bb2   = (const float*)d_in[12];
    float* out = (float*)d_out;

    char* ws = (char*)d_ws;
    // [0,64 MiB): y1 fp64 during features; afterwards simbuf fp32 [0,32) + R bf16 [32,48)
    double*         y1   = (double*)(ws);
    float*          simb = (float*)(ws);
    unsigned short* Rp   = (unsigned short*)(ws + 33554432);
    double*         y2   = (double*)(ws + 67108864);        // 32 MiB, live to the end
    double*         pSum = (double*)(ws + 100663296);       // 512 KiB
    double*         pSqs = (double*)(ws + 101187584);       // 512 KiB
    double*         prm  = (double*)(ws + 101711872);       // 6*1024 f64
    double* scale0 = prm;           double* shift0 = prm + 1024;
    double* scale1 = prm + 2048;    double* shift1 = prm + 3072;
    double* scale2 = prm + 4096;    double* shift2 = prm + 5120;
    float*          sqf  = (float*)(ws + 101761024);        // 8192 f32

    dim3 blk(256);
    const int RPB = NROWS / 64;

    // input BN params
    col_stats_partial<float><<<dim3(DIM / 256, 64), blk, 0, stream>>>(x, DIM, RPB, pSum, pSqs);
    col_stats_final<<<dim3(DIM / 256), blk, 0, stream>>>(pSum, pSqs, ibn_g, ibn_b, scale0, shift0, DIM, 64);
    // layer 1 (fp64)
    gemm_affine_tanh<float><<<dim3(HID1 / 64, NROWS / 64), blk, 0, stream>>>(x, scale0, shift0, W1, b1, y1, DIM, HID1);
    col_stats_partial<double><<<dim3(HID1 / 256, 64), blk, 0, stream>>>(y1, HID1, RPB, pSum, pSqs);
    col_stats_final<<<dim3(HID1 / 256), blk, 0, stream>>>(pSum, pSqs, g1, bb1, scale1, shift1, HID1, 64);
    // layer 2 (fp64)
    gemm_affine_tanh<double><<<dim3(HID2 / 64, NROWS / 64), blk, 0, stream>>>(y1, scale1, shift1, W2, b2, y2, HID1, HID2);
    col_stats_partial<double><<<dim3(HID2 / 256, 64), blk, 0, stream>>>(y2, HID2, RPB, pSum, pSqs);
    col_stats_final<<<dim3(HID2 / 256), blk, 0, stream>>>(pSum, pSqs, g2, bb2, scale2, shift2, HID2, 64);
    // pack split-bf16 features + fp32 row norms (y1 now dead; R lives in its region)
    pack_features<<<dim3(NROWS), blk, 0, stream>>>(y2, scale2, shift2, Rp, sqf);
    // chunked MFMA sim + topk with fp64 band refinement
    for (int ch = 0; ch < 8; ++ch) {
        int rowBase = ch * 1024;
        sim_mfma<<<dim3(NROWS / 128, 1024 / 128), blk, 0, stream>>>(Rp, sqf, simb, rowBase);
        topk_refine<<<dim3(1024), blk, 0, stream>>>(simb, y2, scale2, shift2, y_n, out, rowBase);
    }
}

// Round 4
// 1346.923 us; speedup vs baseline: 2.5210x; 1.0690x over previous
//
#include <hip/hip_runtime.h>
#include <math.h>

#define NROWS 8192
#define DIM   512
#define HID1  1024
#define HID2  512
#define NCLS  10
#define KTOP  64
#define KPACK 1024      // packed row: [hi(512) | lo(512)]
#define KFULL 1536      // logical GEMM K: hi*hi + hi*lo + lo*hi
#define EPSBAND 0.02f   // d2 ambiguity half-band; approx err <= ~2e-3

typedef __attribute__((ext_vector_type(8))) short short8;
typedef __attribute__((ext_vector_type(4))) float f32x4;
typedef __attribute__((ext_vector_type(4))) double f64x4;

__device__ __forceinline__ unsigned short f2bf(float x) {
    unsigned u = __float_as_uint(x);
    u += 0x7FFFu + ((u >> 16) & 1u);   // RN-even
    return (unsigned short)(u >> 16);
}
__device__ __forceinline__ float bf2f(unsigned short h) {
    return __uint_as_float(((unsigned)h) << 16);
}

// ---------------- column stats (mean/var over batch), fp64 ----------------
template <typename T>
__global__ __launch_bounds__(256) void col_stats_partial(
    const T* __restrict__ A, int F, int rowsPerBlock,
    double* __restrict__ pSum, double* __restrict__ pSqs)
{
    int c  = blockIdx.x * 256 + threadIdx.x;
    int r0 = blockIdx.y * rowsPerBlock;
    double s = 0.0, s2 = 0.0;
    for (int r = r0; r < r0 + rowsPerBlock; ++r) {
        double v = (double)A[(size_t)r * F + c];
        s  += v;
        s2 += v * v;
    }
    pSum[(size_t)blockIdx.y * F + c] = s;
    pSqs[(size_t)blockIdx.y * F + c] = s2;
}

__global__ __launch_bounds__(256) void col_stats_final(
    const double* __restrict__ pSum, const double* __restrict__ pSqs,
    const float* __restrict__ g, const float* __restrict__ b,
    double* __restrict__ scale, double* __restrict__ shift, int F, int nPart)
{
    int c = blockIdx.x * 256 + threadIdx.x;
    double s = 0.0, s2 = 0.0;
    for (int p = 0; p < nPart; ++p) {
        s  += pSum[(size_t)p * F + c];
        s2 += pSqs[(size_t)p * F + c];
    }
    double mean = s * (1.0 / NROWS);
    double var  = s2 * (1.0 / NROWS) - mean * mean;
    double sc   = (double)g[c] / sqrt(var + 1e-5);
    scale[c] = sc;
    shift[c] = (double)b[c] - mean * sc;
}

// ---------------- f64-MFMA: out = tanh( affine(A) @ W^T + bias ), fp64 ----------------
// Tile 64(M)x64(N), 4 waves (wave w = rows w*16..w*16+15), K-chunk 32.
// LDS k-major [k][66] so A-read aT[k][row] and B-read bT[k][col] are b64-minimal.
template <typename T>
__global__ __launch_bounds__(256) void gemm_mfma_tanh(
    const T* __restrict__ A, const double* __restrict__ scl, const double* __restrict__ sft,
    const float* __restrict__ W, const float* __restrict__ bias,
    double* __restrict__ out, int Kd, int F)
{
    __shared__ double aS[32 * 66];
    __shared__ double bS[32 * 66];
    const int t = threadIdx.x;
    const int lane = t & 63;
    const int wv = t >> 6;
    const int fBase = blockIdx.x * 64;
    const int mBase = blockIdx.y * 64;
    const int srow = t >> 2;          // 0..63 (M-row for A, N-col for B)
    const int skq  = (t & 3) * 8;     // k offset 0,8,16,24

    f64x4 acc[4];
    #pragma unroll
    for (int n = 0; n < 4; ++n) acc[n] = (f64x4){0.0, 0.0, 0.0, 0.0};

    const int nChunks = Kd >> 5;
    for (int ch = 0; ch < nChunks; ++ch) {
        const int kb = ch << 5;
        // ---- stage A (affine applied) ----
        double av[8];
        if constexpr (sizeof(T) == 4) {
            const float4* ap = (const float4*)&A[(size_t)(mBase + srow) * Kd + kb + skq];
            float4 a0 = ap[0], a1 = ap[1];
            av[0] = a0.x; av[1] = a0.y; av[2] = a0.z; av[3] = a0.w;
            av[4] = a1.x; av[5] = a1.y; av[6] = a1.z; av[7] = a1.w;
        } else {
            const double2* ap = (const double2*)&A[(size_t)(mBase + srow) * Kd + kb + skq];
            double2 d0 = ap[0], d1 = ap[1], d2 = ap[2], d3 = ap[3];
            av[0] = d0.x; av[1] = d0.y; av[2] = d1.x; av[3] = d1.y;
            av[4] = d2.x; av[5] = d2.y; av[6] = d3.x; av[7] = d3.y;
        }
        #pragma unroll
        for (int i = 0; i < 8; ++i)
            av[i] = av[i] * scl[kb + skq + i] + sft[kb + skq + i];
        #pragma unroll
        for (int i = 0; i < 8; ++i)
            aS[(skq + i) * 66 + srow] = av[i];
        // ---- stage B = W[fBase+col][k] as fp64 ----
        const float4* wp = (const float4*)&W[(size_t)(fBase + srow) * Kd + kb + skq];
        float4 w0 = wp[0], w1 = wp[1];
        bS[(skq + 0) * 66 + srow] = (double)w0.x;
        bS[(skq + 1) * 66 + srow] = (double)w0.y;
        bS[(skq + 2) * 66 + srow] = (double)w0.z;
        bS[(skq + 3) * 66 + srow] = (double)w0.w;
        bS[(skq + 4) * 66 + srow] = (double)w1.x;
        bS[(skq + 5) * 66 + srow] = (double)w1.y;
        bS[(skq + 6) * 66 + srow] = (double)w1.z;
        bS[(skq + 7) * 66 + srow] = (double)w1.w;
        __syncthreads();
        // ---- MFMA over the chunk ----
        #pragma unroll
        for (int k4 = 0; k4 < 8; ++k4) {
            const int kk = k4 * 4 + (lane >> 4);
            double a = aS[kk * 66 + wv * 16 + (lane & 15)];
            #pragma unroll
            for (int n = 0; n < 4; ++n) {
                double b = bS[kk * 66 + n * 16 + (lane & 15)];
                acc[n] = __builtin_amdgcn_mfma_f64_16x16x4f64(a, b, acc[n], 0, 0, 0);
            }
        }
        __syncthreads();
    }

    // ---- epilogue: bias + tanh, fp64 store ----
    #pragma unroll
    for (int n = 0; n < 4; ++n) {
        const int f = fBase + n * 16 + (lane & 15);
        const double bz = (double)bias[f];
        #pragma unroll
        for (int r = 0; r < 4; ++r) {
            const int m = mBase + wv * 16 + (lane >> 4) * 4 + r;
            out[(size_t)m * F + f] = tanh(acc[n][r] + bz);
        }
    }
}

// ---------------- pack: f = y2*scl+sft (fp64) -> R=[hi|lo] bf16, sqf fp32 ----------------
__global__ __launch_bounds__(256) void pack_features(
    const double* __restrict__ y2, const double* __restrict__ scl, const double* __restrict__ sft,
    unsigned short* __restrict__ R, float* __restrict__ sqf)
{
    __shared__ double red[4];
    const int r = blockIdx.x;
    const int t = threadIdx.x;
    const int wid = t >> 6, lane = t & 63;
    const int c = t * 2;
    double2 y  = *(const double2*)&y2[(size_t)r * HID2 + c];
    double2 s2 = *(const double2*)&scl[c];
    double2 h2 = *(const double2*)&sft[c];
    double f0 = y.x * s2.x + h2.x;
    double f1 = y.y * s2.y + h2.y;
    unsigned short hi0 = f2bf((float)f0);
    unsigned short hi1 = f2bf((float)f1);
    unsigned short lo0 = f2bf((float)(f0 - (double)bf2f(hi0)));
    unsigned short lo1 = f2bf((float)(f1 - (double)bf2f(hi1)));
    unsigned short* Rr = R + (size_t)r * KPACK;
    Rr[c]           = hi0; Rr[c + 1]           = hi1;
    Rr[HID2 + c]    = lo0; Rr[HID2 + c + 1]    = lo1;
    double s = f0 * f0 + f1 * f1;
    #pragma unroll
    for (int off = 32; off > 0; off >>= 1) s += __shfl_down(s, off);
    if (lane == 0) red[wid] = s;
    __syncthreads();
    if (t == 0) sqf[r] = (float)(red[0] + red[1] + red[2] + red[3]);
}

// ---------------- sim chunk via bf16 MFMA: simbuf[i][j] = -(d2 approx) ----------------
__global__ __launch_bounds__(256) void sim_mfma(
    const unsigned short* __restrict__ R, const float* __restrict__ sqf,
    float* __restrict__ simbuf, int rowBase)
{
    __shared__ unsigned short aT[128 * 64];
    __shared__ unsigned short bT[128 * 64];
    const int t = threadIdx.x;
    const int wid = t >> 6, lane = t & 63;
    const int wr = wid >> 1, wc = wid & 1;
    const int iBase = rowBase + blockIdx.y * 128;
    const int jBase = blockIdx.x * 128;
    const int srow = lane >> 3;          // 0..7
    const int skk  = (lane & 7) * 8;     // k element offset within 64

    f32x4 zero = {0.f, 0.f, 0.f, 0.f};
    f32x4 acc[4][4];
    #pragma unroll
    for (int m = 0; m < 4; ++m)
        #pragma unroll
        for (int n = 0; n < 4; ++n) acc[m][n] = zero;

    for (int k0 = 0; k0 < KFULL; k0 += 64) {
        const int aSrc = (k0 < 512)  ? k0 : (k0 - 512);   // [hi, hi, lo]
        const int bSrc = (k0 < 1024) ? k0 : (k0 - 1024);  // [hi, lo, hi]
        #pragma unroll
        for (int c = 0; c < 4; ++c) {
            int row = c * 32 + wid * 8 + srow;
            const unsigned short* gpA = R + (size_t)(iBase + row) * KPACK + aSrc + skk;
            const unsigned short* gpB = R + (size_t)(jBase + row) * KPACK + bSrc + skk;
            unsigned short* lpA = &aT[(c * 4 + wid) * 512];  // wave-uniform base
            unsigned short* lpB = &bT[(c * 4 + wid) * 512];
            __builtin_amdgcn_global_load_lds((const __attribute__((address_space(1))) void*)gpA,
                (__attribute__((address_space(3))) void*)lpA, 16, 0, 0);
            __builtin_amdgcn_global_load_lds((const __attribute__((address_space(1))) void*)gpB,
                (__attribute__((address_space(3))) void*)lpB, 16, 0, 0);
        }
        __syncthreads();
        #pragma unroll
        for (int ks = 0; ks < 2; ++ks) {
            short8 aF[4], bF[4];
            #pragma unroll
            for (int m = 0; m < 4; ++m) {
                int rA = wr * 64 + m * 16 + (lane & 15);
                aF[m] = *(const short8*)&aT[rA * 64 + ks * 32 + (lane >> 4) * 8];
            }
            #pragma unroll
            for (int n = 0; n < 4; ++n) {
                int rB = wc * 64 + n * 16 + (lane & 15);
                bF[n] = *(const short8*)&bT[rB * 64 + ks * 32 + (lane >> 4) * 8];
            }
            #pragma unroll
            for (int m = 0; m < 4; ++m)
                #pragma unroll
                for (int n = 0; n < 4; ++n)
                    acc[m][n] = __builtin_amdgcn_mfma_f32_16x16x32_bf16(aF[m], bF[n], acc[m][n], 0, 0, 0);
        }
        __syncthreads();
    }

    #pragma unroll
    for (int m = 0; m < 4; ++m) {
        #pragma unroll
        for (int n = 0; n < 4; ++n) {
            int j = jBase + wc * 64 + n * 16 + (lane & 15);
            float sqj = sqf[j];
            #pragma unroll
            for (int r = 0; r < 4; ++r) {
                int i = iBase + wr * 64 + m * 16 + (lane >> 4) * 4 + r;
                float d2 = sqf[i] + sqj - 2.0f * acc[m][n][r];
                d2 = fmaxf(d2, 0.f);
                float s = (i == j) ? -INFINITY : -d2;
                simbuf[(size_t)(i - rowBase) * NROWS + j] = s;
            }
        }
    }
}

// ---------------- top-K (fp32 rank) + fp64 band refinement + softmax ----------------
__device__ __forceinline__ unsigned fKey(float v) {
    unsigned b = __float_as_uint(v);
    return (b & 0x80000000u) ? ~b : (b | 0x80000000u);
}
__device__ __forceinline__ float keyToFloat(unsigned k) {
    unsigned b = (k & 0x80000000u) ? (k ^ 0x80000000u) : ~k;
    return __uint_as_float(b);
}

__global__ __launch_bounds__(256) void topk_refine(
    const float* __restrict__ simbuf,
    const double* __restrict__ y2, const double* __restrict__ scl, const double* __restrict__ sft,
    const int* __restrict__ labels, float* __restrict__ out, int rowBase)
{
    __shared__ int      redI[4];
    __shared__ unsigned redU[4];
    __shared__ float    redF[4];
    __shared__ float    cls[NCLS];
    __shared__ int      bandJ[128];
    __shared__ double   bandD2[128];
    __shared__ unsigned char keepB[128];
    __shared__ int      bandCnt;

    const int t = threadIdx.x;
    const int wid = t >> 6, lane = t & 63;
    const int row = blockIdx.x;
    const int gi = rowBase + row;
    const float* srow = simbuf + (size_t)row * NROWS;

    unsigned key[32];
    #pragma unroll
    for (int ii = 0; ii < 32; ++ii) key[ii] = fKey(srow[t + ii * 256]);

    // global row max (nearest neighbor), fp32 approx — common softmax shift
    unsigned kmax = 0u;
    #pragma unroll
    for (int ii = 0; ii < 32; ++ii) kmax = max(kmax, key[ii]);
    #pragma unroll
    for (int off = 32; off > 0; off >>= 1) kmax = max(kmax, (unsigned)__shfl_down(kmax, off));
    if (lane == 0) redU[wid] = kmax;
    if (t == 0) bandCnt = 0;
    if (t < NCLS) cls[t] = 0.f;
    __syncthreads();
    kmax = max(max(redU[0], redU[1]), max(redU[2], redU[3]));
    float d2min = fmaxf(-keyToFloat(kmax), 0.f);
    float distMin = (d2min > 1e-9f) ? sqrtf(d2min) : 0.f;
    __syncthreads();

    // binary search: T64 = 64th largest fp32 key
    unsigned lo = 0u, hi = 0xFFFFFFFFu;
    while (lo < hi) {
        unsigned mid = (unsigned)(((unsigned long long)lo + hi + 1ull) >> 1);
        int cnt = 0;
        #pragma unroll
        for (int ii = 0; ii < 32; ++ii) cnt += (key[ii] >= mid) ? 1 : 0;
        #pragma unroll
        for (int off = 32; off > 0; off >>= 1) cnt += __shfl_down(cnt, off);
        if (lane == 0) redI[wid] = cnt;
        __syncthreads();
        int tot = redI[0] + redI[1] + redI[2] + redI[3];
        __syncthreads();
        if (tot >= KTOP) lo = mid; else hi = mid - 1u;
    }
    const float s64 = keyToFloat(lo);
    const unsigned Ku = fKey(s64 + EPSBAND);
    const unsigned Kl = fKey(s64 - EPSBAND);

    // nSafe = count(key >= Ku): definitely in true top-64
    int cnt = 0;
    #pragma unroll
    for (int ii = 0; ii < 32; ++ii) cnt += (key[ii] >= Ku) ? 1 : 0;
    #pragma unroll
    for (int off = 32; off > 0; off >>= 1) cnt += __shfl_down(cnt, off);
    if (lane == 0) redI[wid] = cnt;
    __syncthreads();
    const int nSafe = redI[0] + redI[1] + redI[2] + redI[3];
    const int Rslots = KTOP - nSafe;

    // collect ambiguous band: Kl <= key < Ku
    #pragma unroll
    for (int ii = 0; ii < 32; ++ii) {
        if (key[ii] >= Kl && key[ii] < Ku) {
            int pos = atomicAdd(&bandCnt, 1);
            if (pos < 128) bandJ[pos] = t + ii * 256;
        }
    }
    __syncthreads();
    const int nb = min(bandCnt, 128);

    // exact fp64 d2 for band members (one wave per member)
    for (int c2 = wid; c2 < nb; c2 += 4) {
        int j = bandJ[c2];
        double s = 0.0;
        for (int d = lane; d < HID2; d += 64) {
            double sc = scl[d], sh = sft[d];
            double fi = y2[(size_t)gi * HID2 + d] * sc + sh;
            double fj = y2[(size_t)j  * HID2 + d] * sc + sh;
            double df = fi - fj;
            s += df * df;
        }
        #pragma unroll
        for (int off = 32; off > 0; off >>= 1) s += __shfl_down(s, off);
        if (lane == 0) bandD2[c2] = s;
    }
    __syncthreads();

    // rank band by (d2 asc, index asc); keep top Rslots
    for (int c2 = t; c2 < nb; c2 += 256) {
        double d2c = bandD2[c2];
        int jc = bandJ[c2];
        int rank = 0;
        for (int q = 0; q < nb; ++q) {
            double dq = bandD2[q];
            rank += (dq < d2c || (dq == d2c && bandJ[q] < jc)) ? 1 : 0;
        }
        keepB[c2] = (rank < Rslots) ? 1 : 0;
    }
    __syncthreads();

    // softmax accumulate: safe set (fp32 d2) + kept band (fp64 d2)
    float S = 0.f;
    #pragma unroll
    for (int ii = 0; ii < 32; ++ii) {
        if (key[ii] >= Ku) {
            float d2 = -keyToFloat(key[ii]);
            float dist = (d2 > 1e-9f) ? sqrtf(d2) : 0.f;
            float w = expf(distMin - dist);
            S += w;
            atomicAdd(&cls[labels[t + ii * 256]], w);
        }
    }
    for (int c2 = t; c2 < nb; c2 += 256) {
        if (keepB[c2]) {
            double dd = bandD2[c2];
            float dist = (dd > 1e-9) ? (float)sqrt(dd) : 0.f;
            float w = expf(distMin - dist);
            S += w;
            atomicAdd(&cls[labels[bandJ[c2]]], w);
        }
    }
    #pragma unroll
    for (int off = 32; off > 0; off >>= 1) S += __shfl_down(S, off);
    if (lane == 0) redF[wid] = S;
    __syncthreads();
    float Stot = redF[0] + redF[1] + redF[2] + redF[3];

    if (t < NCLS) {
        float p = cls[t] / Stot;
        out[(size_t)gi * NCLS + t] = fminf(fmaxf(p, 0.f), 1.f);
    }
}

extern "C" void kernel_launch(void* const* d_in, const int* in_sizes, int n_in,
                              void* d_out, int out_size, void* d_ws, size_t ws_size,
                              hipStream_t stream)
{
    const float* x     = (const float*)d_in[0];
    // d_in[1] = x_n == x bit-exactly (self-neighbor mode) -> features computed once
    const int*   y_n   = (const int*)d_in[2];
    const float* ibn_g = (const float*)d_in[3];
    const float* ibn_b = (const float*)d_in[4];
    const float* W1    = (const float*)d_in[5];
    const float* b1    = (const float*)d_in[6];
    const float* g1    = (const float*)d_in[7];
    const float* bb1   = (const float*)d_in[8];
    const float* W2    = (const float*)d_in[9];
    const float* b2    = (const float*)d_in[10];
    const float* g2    = (const float*)d_in[11];
    const float* bb2   = (const float*)d_in[12];
    float* out = (float*)d_out;

    char* ws = (char*)d_ws;
    // [0,64 MiB): y1 fp64 during features; afterwards simbuf fp32 [0,32) + R bf16 [32,48)
    double*         y1   = (double*)(ws);
    float*          simb = (float*)(ws);
    unsigned short* Rp   = (unsigned short*)(ws + 33554432);
    double*         y2   = (double*)(ws + 67108864);        // 32 MiB, live to the end
    double*         pSum = (double*)(ws + 100663296);       // 512 KiB
    double*         pSqs = (double*)(ws + 101187584);       // 512 KiB
    double*         prm  = (double*)(ws + 101711872);       // 6*1024 f64
    double* scale0 = prm;           double* shift0 = prm + 1024;
    double* scale1 = prm + 2048;    double* shift1 = prm + 3072;
    double* scale2 = prm + 4096;    double* shift2 = prm + 5120;
    float*          sqf  = (float*)(ws + 101761024);        // 8192 f32

    dim3 blk(256);
    const int RPB = NROWS / 64;

    // input BN params
    col_stats_partial<float><<<dim3(DIM / 256, 64), blk, 0, stream>>>(x, DIM, RPB, pSum, pSqs);
    col_stats_final<<<dim3(DIM / 256), blk, 0, stream>>>(pSum, pSqs, ibn_g, ibn_b, scale0, shift0, DIM, 64);
    // layer 1 (f64 MFMA)
    gemm_mfma_tanh<float><<<dim3(HID1 / 64, NROWS / 64), blk, 0, stream>>>(x, scale0, shift0, W1, b1, y1, DIM, HID1);
    col_stats_partial<double><<<dim3(HID1 / 256, 64), blk, 0, stream>>>(y1, HID1, RPB, pSum, pSqs);
    col_stats_final<<<dim3(HID1 / 256), blk, 0, stream>>>(pSum, pSqs, g1, bb1, scale1, shift1, HID1, 64);
    // layer 2 (f64 MFMA)
    gemm_mfma_tanh<double><<<dim3(HID2 / 64, NROWS / 64), blk, 0, stream>>>(y1, scale1, shift1, W2, b2, y2, HID1, HID2);
    col_stats_partial<double><<<dim3(HID2 / 256, 64), blk, 0, stream>>>(y2, HID2, RPB, pSum, pSqs);
    col_stats_final<<<dim3(HID2 / 256), blk, 0, stream>>>(pSum, pSqs, g2, bb2, scale2, shift2, HID2, 64);
    // pack split-bf16 features + fp32 row norms (y1 now dead; R lives in its region)
    pack_features<<<dim3(NROWS), blk, 0, stream>>>(y2, scale2, shift2, Rp, sqf);
    // chunked MFMA sim + topk with fp64 band refinement
    for (int ch = 0; ch < 8; ++ch) {
        int rowBase = ch * 1024;
        sim_mfma<<<dim3(NROWS / 128, 1024 / 128), blk, 0, stream>>>(Rp, sqf, simb, rowBase);
        topk_refine<<<dim3(1024), blk, 0, stream>>>(simb, y2, scale2, shift2, y_n, out, rowBase);
    }
}